// Round 3
// baseline (452.327 us; speedup 1.0000x reference)
//
#include <hip/hip_runtime.h>
#include <math.h>

// Problem constants (fixed by the reference):
#define BB 32     // batch
#define NN 128    // nodes
#define CC 16     // in_ch
#define OO 32     // out_ch
#define II 32     // in_dim
#define JJ 32     // out_dim
#define MM (NN*CC)  // 2048 input capsules per (b, out_ch)
static constexpr float EPS_ = 1e-11f;

// The routing recurrence is INDEPENDENT per (b,o): softmax is over the 2048
// capsules of one (b,o) row, squash is per (b,o), and the agreement update
// touches only bij[b,:,o]. So one block owns a (b, o-pair) end-to-end:
// bij lives in LDS (16 KB), cx/v/wv/stats live in LDS, and the only global
// arrays are x (via a one-time transpose xT) and W. Two dispatches total.
//
// Workspace: xT [BB][CC][II][NN] = 8 MB. Natural XCD affinity: blockIdx&31=b
// -> bid%8 = b%8, so each XCD serves 4 b's (1 MB of xT) from its L2.

// ---- one-time transpose: xT[b][c][i][n] = x[b][n][c][i] ----
__global__ __launch_bounds__(1024) void k_transpose(
    const float* __restrict__ x, float* __restrict__ xT) {
  int b = blockIdx.x >> 4, c = blockIdx.x & 15;
  __shared__ __align__(16) float xsT[II][NN + 4];   // +4: f4-aligned padded rows
  int tid = threadIdx.x;
  {
    int n = tid >> 3, i4 = (tid & 7) * 4;
    float4 v = *(const float4*)(x + (((size_t)(b * NN + n)) * CC + c) * II + i4);
    xsT[i4 + 0][n] = v.x; xsT[i4 + 1][n] = v.y;
    xsT[i4 + 2][n] = v.z; xsT[i4 + 3][n] = v.w;
  }
  __syncthreads();
  {
    int i = tid >> 5, n4 = tid & 31;
    float4 v = *(const float4*)(&xsT[i][n4 * 4]);   // row stride 528 B, 16B-aligned
    ((float4*)(xT + ((size_t)(b * CC + c)) * II * NN))[tid] = v;
  }
}

// ---- the whole routing loop. Block per (b, o-pair). 1024 threads. ----
__global__ __launch_bounds__(1024, 8) void k_route(
    const float* __restrict__ xT, const float* __restrict__ W,
    float* __restrict__ out) {
  int bid = blockIdx.x;
  int b = bid & 31, o0 = (bid >> 5) * 2;      // o-pair {o0, o0+1}
  int tid = threadIdx.x;

  __shared__ __align__(16) float bijL[2][CC][NN];   // 16 KB routing logits
  __shared__ __align__(16) float coef[2][CC][NN];   // 16 KB softmax coefs
  __shared__ float cxs[2][CC][II];                  // 4 KB
  __shared__ float wv [2][CC][II];                  // 4 KB
  __shared__ float partA[2][CC][JJ];                // 4 KB
  __shared__ float vs[2][JJ];
  __shared__ float redM[CC][2];
  __shared__ float smx[2], srin[2];
  // total ~45 KB -> 2 blocks/CU, 32 waves/CU

  {  // bijL = 0 (first U adds it; matches reference b_ij=0 start)
    int o = tid >> 9, c = (tid >> 5) & 15, n4 = tid & 31;
    *(float4*)(&bijL[o][c][n4 * 4]) = make_float4(0.f, 0.f, 0.f, 0.f);
  }

  const float4* xTb = (const float4*)(xT + (size_t)b * CC * II * NN);
  // f4 index within b: c*1024 + i*32 + nf4

  for (int it = 0; it < 3; ++it) {
    // --- preC: coef[o][c][n] = softmax coefficient (uniform on iter 0) ---
    {
      int o = tid >> 9, c = (tid >> 5) & 15, n4 = tid & 31;
      float4 cf;
      if (it == 0) {
        float u = 1.0f / (float)MM;
        cf = make_float4(u, u, u, u);
      } else {
        float4 bb = *(const float4*)(&bijL[o][c][n4 * 4]);
        float m = smx[o], r = srin[o];
        cf.x = __expf(bb.x - m) * r; cf.y = __expf(bb.y - m) * r;
        cf.z = __expf(bb.z - m) * r; cf.w = __expf(bb.w - m) * r;
      }
      *(float4*)(&coef[o][c][n4 * 4]) = cf;
    }
    __syncthreads();

    // --- C: cxs[o][c][i] = sum_n coef[o][c][n] * xT[b][c][i][n] ---
    // wave = one c; lane (i, s-half of n); coef reads are 2-addr broadcasts.
    {
      int c = tid >> 6, l = tid & 63, i = l >> 1, s = l & 1;
      const float4* xr = xTb + c * (II * NN / 4) + i * (NN / 4) + s * 16;
      const float4* c0 = (const float4*)(&coef[0][c][s * 64]);
      const float4* c1 = (const float4*)(&coef[1][c][s * 64]);
      float a0 = 0.f, a1 = 0.f;
      #pragma unroll
      for (int q = 0; q < 16; ++q) {
        float4 xv = xr[q];
        float4 f0 = c0[q], f1 = c1[q];
        a0 += xv.x * f0.x + xv.y * f0.y + xv.z * f0.z + xv.w * f0.w;
        a1 += xv.x * f1.x + xv.y * f1.y + xv.z * f1.z + xv.w * f1.w;
      }
      a0 += __shfl_xor(a0, 1);           // combine n-halves (s-pair lanes)
      a1 += __shfl_xor(a1, 1);
      cxs[s][c][i] = (s == 0) ? a0 : a1; // lane s owns o=s
    }
    __syncthreads();

    // --- A: partA[o][c][j] = sum_i cxs[o][c][i] * W[c][o0+o][i][j] ---
    {
      int o = tid >> 9, c = (tid >> 5) & 15, j = tid & 31;
      const float* Wp = W + (((size_t)(c * OO + o0 + o)) * II) * JJ + j;
      float acc = 0.f;
      #pragma unroll
      for (int i = 0; i < II; ++i)
        acc += cxs[o][c][i] * Wp[i * JJ];   // cxs broadcast, W j-coalesced
      partA[o][c][j] = acc;
    }
    __syncthreads();

    // --- A-reduce + squash (final iter writes output) ---
    if (tid < 64) {
      int o = tid >> 5, j = tid & 31;
      float s = 0.f;
      #pragma unroll
      for (int c = 0; c < CC; ++c) s += partA[o][c][j];
      float msq = s * s;
      #pragma unroll
      for (int off = 16; off > 0; off >>= 1) msq += __shfl_xor(msq, off);
      float mag = sqrtf(msq) + EPS_;
      float a   = msq / (1.0f + msq);
      float vv  = a * s / mag;
      if (it == 2) {
        int row = b * OO + (o0 + o);
        out[(size_t)row * JJ + j] = vv;                // v_j: [B,1,O,J] flat
        if (j == 0) out[BB * OO * JJ + row] = a;       // a_j: [B,1,O,1] flat
      } else {
        vs[o][j] = vv;
      }
    }
    if (it == 2) break;                   // uniform exit
    __syncthreads();

    // --- Wv: wv[o][c][i] = sum_j W[c][o0+o][i][j] * vs[o][j] ---
    {
      int o = tid >> 9, c = (tid >> 5) & 15, i = tid & 31;
      const float4* Wr = (const float4*)(W + (((size_t)(c * OO + o0 + o)) * II + i) * JJ);
      float acc = 0.f;
      #pragma unroll
      for (int q = 0; q < 8; ++q) {
        float4 w4 = Wr[q];
        acc += w4.x * vs[o][q*4+0] + w4.y * vs[o][q*4+1]
             + w4.z * vs[o][q*4+2] + w4.w * vs[o][q*4+3];
      }
      wv[o][c][i] = acc;
    }
    __syncthreads();

    // --- U: bijL[o][c][n] += sum_i xT[b][c][i][n]*wv[o][c][i]; then stats ---
    // lane (c, n4, s-half of i); xT f4 reads shared by BOTH o's; 512B runs.
    {
      int c = tid >> 6, n4 = (tid >> 1) & 31, s = tid & 1;
      float4 ac0 = make_float4(0.f,0.f,0.f,0.f);
      float4 ac1 = make_float4(0.f,0.f,0.f,0.f);
      #pragma unroll
      for (int q = 0; q < 16; ++q) {
        int i = s * 16 + q;
        float4 xv = xTb[c * (II * NN / 4) + i * (NN / 4) + n4];
        float w0 = wv[0][c][i], w1 = wv[1][c][i];   // broadcasts
        ac0.x += xv.x * w0; ac0.y += xv.y * w0; ac0.z += xv.z * w0; ac0.w += xv.w * w0;
        ac1.x += xv.x * w1; ac1.y += xv.y * w1; ac1.z += xv.z * w1; ac1.w += xv.w * w1;
      }
      // combine i-halves across the s-pair
      ac0.x += __shfl_xor(ac0.x, 1); ac0.y += __shfl_xor(ac0.y, 1);
      ac0.z += __shfl_xor(ac0.z, 1); ac0.w += __shfl_xor(ac0.w, 1);
      ac1.x += __shfl_xor(ac1.x, 1); ac1.y += __shfl_xor(ac1.y, 1);
      ac1.z += __shfl_xor(ac1.z, 1); ac1.w += __shfl_xor(ac1.w, 1);
      float4 r = (s == 0) ? ac0 : ac1;              // lane s owns o=s
      float4 bb = *(const float4*)(&bijL[s][c][n4 * 4]);
      r.x += bb.x; r.y += bb.y; r.z += bb.z; r.w += bb.w;
      *(float4*)(&bijL[s][c][n4 * 4]) = r;

      // softmax stats for the NEXT iteration (row fully block-owned)
      float m4 = fmaxf(fmaxf(r.x, r.y), fmaxf(r.z, r.w));
      #pragma unroll
      for (int off = 2; off <= 32; off <<= 1)       // parity-preserving reduce
        m4 = fmaxf(m4, __shfl_xor(m4, off));
      if ((tid & 63) <= 1) redM[c][s] = m4;         // lane 0: o=0, lane 1: o=1
      __syncthreads();
      if (tid < 2) {
        float m = redM[0][tid];
        #pragma unroll
        for (int w2 = 1; w2 < CC; ++w2) m = fmaxf(m, redM[w2][tid]);
        smx[tid] = m;
      }
      __syncthreads();
      float mo = smx[s];
      float e = __expf(r.x - mo) + __expf(r.y - mo)
              + __expf(r.z - mo) + __expf(r.w - mo);
      #pragma unroll
      for (int off = 2; off <= 32; off <<= 1) e += __shfl_xor(e, off);
      if ((tid & 63) <= 1) redM[c][s] = e;
      __syncthreads();
      if (tid < 2) {
        float ss = 0.f;
        #pragma unroll
        for (int w2 = 0; w2 < CC; ++w2) ss += redM[w2][tid];
        srin[tid] = 1.0f / ss;
      }
    }
    __syncthreads();
  }
}

extern "C" void kernel_launch(void* const* d_in, const int* in_sizes, int n_in,
                              void* d_out, int out_size, void* d_ws, size_t ws_size,
                              hipStream_t stream) {
  const float* x = (const float*)d_in[0];   // [B,N,C,I]
  const float* W = (const float*)d_in[1];   // [C,O,I,J]
  (void)in_sizes; (void)n_in;               // d_in[2] = number_of_nodes (fixed 128)
  float* out = (float*)d_out; (void)out_size;

  float* xT = (float*)d_ws;                 // 2,097,152 floats (8 MB)
  (void)ws_size;

  k_transpose<<<BB * CC, 1024, 0, stream>>>(x, xT);
  k_route<<<BB * (OO / 2), 1024, 0, stream>>>(xT, W, out);
}

// Round 4
// 262.948 us; speedup vs baseline: 1.7202x; 1.7202x over previous
//
#include <hip/hip_runtime.h>
#include <math.h>

// Problem constants (fixed by the reference):
#define BB 32     // batch
#define NN 128    // nodes
#define CC 16     // in_ch
#define OO 32     // out_ch
#define II 32     // in_dim
#define JJ 32     // out_dim
#define MM (NN*CC)  // 2048 input capsules per (b, out_ch)
static constexpr float EPS_ = 1e-11f;

// The routing recurrence is INDEPENDENT per (b,o): softmax is over the 2048
// capsules of one (b,o) row, squash is per (b,o), and the agreement update
// touches only bij[b,:,o]. So one block owns a (b, o-pair) end-to-end:
// bij lives in LDS (16 KB), cx/v/wv/stats live in LDS, and the only global
// arrays are x (via a one-time transpose xT) and W. Two dispatches total.
//
// REGISTER PRESSURE (round-3 lesson): do NOT force min-waves. 1024-thread
// blocks already cap VGPR at 128 (16 waves must fit a SIMD's 512-reg file);
// forcing 8 waves/SIMD pushed the cap to 64, the allocator hit 32, and the
// float4 phases spilled ~1 KB/thread -> 1 GB/dispatch of scratch HBM traffic
// (FETCH 557 MB + WRITE 483 MB measured). Plain __launch_bounds__(1024).

// ---- one-time transpose: xT[b][c][i][n] = x[b][n][c][i] ----
__global__ __launch_bounds__(1024) void k_transpose(
    const float* __restrict__ x, float* __restrict__ xT) {
  int b = blockIdx.x >> 4, c = blockIdx.x & 15;
  __shared__ __align__(16) float xsT[II][NN + 4];   // +4: f4-aligned padded rows
  int tid = threadIdx.x;
  {
    int n = tid >> 3, i4 = (tid & 7) * 4;
    float4 v = *(const float4*)(x + (((size_t)(b * NN + n)) * CC + c) * II + i4);
    xsT[i4 + 0][n] = v.x; xsT[i4 + 1][n] = v.y;
    xsT[i4 + 2][n] = v.z; xsT[i4 + 3][n] = v.w;
  }
  __syncthreads();
  {
    int i = tid >> 5, n4 = tid & 31;
    float4 v = *(const float4*)(&xsT[i][n4 * 4]);   // row stride 528 B, 16B-aligned
    ((float4*)(xT + ((size_t)(b * CC + c)) * II * NN))[tid] = v;
  }
}

// ---- the whole routing loop. Block per (b, o-pair). 1024 threads. ----
__global__ __launch_bounds__(1024) void k_route(
    const float* __restrict__ xT, const float* __restrict__ W,
    float* __restrict__ out) {
  int bid = blockIdx.x;
  int b = bid & 31, o0 = (bid >> 5) * 2;      // o-pair {o0, o0+1}
  int tid = threadIdx.x;

  __shared__ __align__(16) float bijL[2][CC][NN];   // 16 KB routing logits
  __shared__ __align__(16) float coef[2][CC][NN];   // 16 KB softmax coefs
  __shared__ float cxs[2][CC][II];                  // 4 KB
  __shared__ float wv [2][CC][II];                  // 4 KB
  __shared__ float partA[2][CC][JJ];                // 4 KB
  __shared__ float vs[2][JJ];
  __shared__ float redM[CC][2];
  __shared__ float smx[2], srin[2];
  // total ~45 KB

  {  // bijL = 0 (first U adds it; matches reference b_ij=0 start)
    int o = tid >> 9, c = (tid >> 5) & 15, n4 = tid & 31;
    *(float4*)(&bijL[o][c][n4 * 4]) = make_float4(0.f, 0.f, 0.f, 0.f);
  }

  const float4* xTb = (const float4*)(xT + (size_t)b * CC * II * NN);
  // f4 index within b: c*1024 + i*32 + nf4

  for (int it = 0; it < 3; ++it) {
    // --- preC: coef[o][c][n] = softmax coefficient (uniform on iter 0) ---
    {
      int o = tid >> 9, c = (tid >> 5) & 15, n4 = tid & 31;
      float4 cf;
      if (it == 0) {
        float u = 1.0f / (float)MM;
        cf = make_float4(u, u, u, u);
      } else {
        float4 bb = *(const float4*)(&bijL[o][c][n4 * 4]);
        float m = smx[o], r = srin[o];
        cf.x = __expf(bb.x - m) * r; cf.y = __expf(bb.y - m) * r;
        cf.z = __expf(bb.z - m) * r; cf.w = __expf(bb.w - m) * r;
      }
      *(float4*)(&coef[o][c][n4 * 4]) = cf;
    }
    __syncthreads();

    // --- C: cxs[o][c][i] = sum_n coef[o][c][n] * xT[b][c][i][n] ---
    // wave = one c; lane (i, s-half of n); coef reads are 2-addr broadcasts.
    {
      int c = tid >> 6, l = tid & 63, i = l >> 1, s = l & 1;
      const float4* xr = xTb + c * (II * NN / 4) + i * (NN / 4) + s * 16;
      const float4* c0 = (const float4*)(&coef[0][c][s * 64]);
      const float4* c1 = (const float4*)(&coef[1][c][s * 64]);
      float a0 = 0.f, a1 = 0.f;
      #pragma unroll
      for (int q = 0; q < 16; ++q) {
        float4 xv = xr[q];
        float4 f0 = c0[q], f1 = c1[q];
        a0 += xv.x * f0.x + xv.y * f0.y + xv.z * f0.z + xv.w * f0.w;
        a1 += xv.x * f1.x + xv.y * f1.y + xv.z * f1.z + xv.w * f1.w;
      }
      a0 += __shfl_xor(a0, 1);           // combine n-halves (s-pair lanes)
      a1 += __shfl_xor(a1, 1);
      cxs[s][c][i] = (s == 0) ? a0 : a1; // lane s owns o=s
    }
    __syncthreads();

    // --- A: partA[o][c][j] = sum_i cxs[o][c][i] * W[c][o0+o][i][j] ---
    {
      int o = tid >> 9, c = (tid >> 5) & 15, j = tid & 31;
      const float* Wp = W + (((size_t)(c * OO + o0 + o)) * II) * JJ + j;
      float acc = 0.f;
      #pragma unroll
      for (int i = 0; i < II; ++i)
        acc += cxs[o][c][i] * Wp[i * JJ];   // cxs broadcast, W j-coalesced
      partA[o][c][j] = acc;
    }
    __syncthreads();

    // --- A-reduce + squash (final iter writes output) ---
    if (tid < 64) {
      int o = tid >> 5, j = tid & 31;
      float s = 0.f;
      #pragma unroll
      for (int c = 0; c < CC; ++c) s += partA[o][c][j];
      float msq = s * s;
      #pragma unroll
      for (int off = 16; off > 0; off >>= 1) msq += __shfl_xor(msq, off);
      float mag = sqrtf(msq) + EPS_;
      float a   = msq / (1.0f + msq);
      float vv  = a * s / mag;
      if (it == 2) {
        int row = b * OO + (o0 + o);
        out[(size_t)row * JJ + j] = vv;                // v_j: [B,1,O,J] flat
        if (j == 0) out[BB * OO * JJ + row] = a;       // a_j: [B,1,O,1] flat
      } else {
        vs[o][j] = vv;
      }
    }
    if (it == 2) break;                   // uniform exit
    __syncthreads();

    // --- Wv: wv[o][c][i] = sum_j W[c][o0+o][i][j] * vs[o][j] ---
    {
      int o = tid >> 9, c = (tid >> 5) & 15, i = tid & 31;
      const float4* Wr = (const float4*)(W + (((size_t)(c * OO + o0 + o)) * II + i) * JJ);
      float acc = 0.f;
      #pragma unroll
      for (int q = 0; q < 8; ++q) {
        float4 w4 = Wr[q];
        acc += w4.x * vs[o][q*4+0] + w4.y * vs[o][q*4+1]
             + w4.z * vs[o][q*4+2] + w4.w * vs[o][q*4+3];
      }
      wv[o][c][i] = acc;
    }
    __syncthreads();

    // --- U: bijL[o][c][n] += sum_i xT[b][c][i][n]*wv[o][c][i]; then stats ---
    // lane (c, n4, s-half of i); xT f4 reads shared by BOTH o's; 512B runs.
    {
      int c = tid >> 6, n4 = (tid >> 1) & 31, s = tid & 1;
      float4 ac0 = make_float4(0.f,0.f,0.f,0.f);
      float4 ac1 = make_float4(0.f,0.f,0.f,0.f);
      #pragma unroll
      for (int q = 0; q < 16; ++q) {
        int i = s * 16 + q;
        float4 xv = xTb[c * (II * NN / 4) + i * (NN / 4) + n4];
        float w0 = wv[0][c][i], w1 = wv[1][c][i];   // broadcasts
        ac0.x += xv.x * w0; ac0.y += xv.y * w0; ac0.z += xv.z * w0; ac0.w += xv.w * w0;
        ac1.x += xv.x * w1; ac1.y += xv.y * w1; ac1.z += xv.z * w1; ac1.w += xv.w * w1;
      }
      // combine i-halves across the s-pair
      ac0.x += __shfl_xor(ac0.x, 1); ac0.y += __shfl_xor(ac0.y, 1);
      ac0.z += __shfl_xor(ac0.z, 1); ac0.w += __shfl_xor(ac0.w, 1);
      ac1.x += __shfl_xor(ac1.x, 1); ac1.y += __shfl_xor(ac1.y, 1);
      ac1.z += __shfl_xor(ac1.z, 1); ac1.w += __shfl_xor(ac1.w, 1);
      float4 r = (s == 0) ? ac0 : ac1;              // lane s owns o=s
      float4 bb = *(const float4*)(&bijL[s][c][n4 * 4]);
      r.x += bb.x; r.y += bb.y; r.z += bb.z; r.w += bb.w;
      *(float4*)(&bijL[s][c][n4 * 4]) = r;

      // softmax stats for the NEXT iteration (row fully block-owned)
      float m4 = fmaxf(fmaxf(r.x, r.y), fmaxf(r.z, r.w));
      #pragma unroll
      for (int off = 2; off <= 32; off <<= 1)       // parity-preserving reduce
        m4 = fmaxf(m4, __shfl_xor(m4, off));
      if ((tid & 63) <= 1) redM[c][s] = m4;         // lane 0: o=0, lane 1: o=1
      __syncthreads();
      if (tid < 2) {
        float m = redM[0][tid];
        #pragma unroll
        for (int w2 = 1; w2 < CC; ++w2) m = fmaxf(m, redM[w2][tid]);
        smx[tid] = m;
      }
      __syncthreads();
      float mo = smx[s];
      float e = __expf(r.x - mo) + __expf(r.y - mo)
              + __expf(r.z - mo) + __expf(r.w - mo);
      #pragma unroll
      for (int off = 2; off <= 32; off <<= 1) e += __shfl_xor(e, off);
      if ((tid & 63) <= 1) redM[c][s] = e;
      __syncthreads();
      if (tid < 2) {
        float ss = 0.f;
        #pragma unroll
        for (int w2 = 0; w2 < CC; ++w2) ss += redM[w2][tid];
        srin[tid] = 1.0f / ss;
      }
    }
    __syncthreads();
  }
}

extern "C" void kernel_launch(void* const* d_in, const int* in_sizes, int n_in,
                              void* d_out, int out_size, void* d_ws, size_t ws_size,
                              hipStream_t stream) {
  const float* x = (const float*)d_in[0];   // [B,N,C,I]
  const float* W = (const float*)d_in[1];   // [C,O,I,J]
  (void)in_sizes; (void)n_in;               // d_in[2] = number_of_nodes (fixed 128)
  float* out = (float*)d_out; (void)out_size;

  float* xT = (float*)d_ws;                 // 2,097,152 floats (8 MB)
  (void)ws_size;

  k_transpose<<<BB * CC, 1024, 0, stream>>>(x, xT);
  k_route<<<BB * (OO / 2), 1024, 0, stream>>>(xT, W, out);
}

// Round 5
// 157.878 us; speedup vs baseline: 2.8650x; 1.6655x over previous
//
#include <hip/hip_runtime.h>
#include <math.h>

// Problem constants (fixed by the reference):
#define BB 32     // batch
#define NN 128    // nodes
#define CC 16     // in_ch
#define OO 32     // out_ch
#define II 32     // in_dim
#define JJ 32     // out_dim
#define MM (NN*CC)  // 2048 input capsules per (b, out_ch)
static constexpr float EPS_ = 1e-11f;

// The routing recurrence is INDEPENDENT per (b,o): one block owns a
// (b, o-pair) end-to-end; bij/coef/cx/v/wv/stats all live in LDS. Only
// global arrays: x (via one-time transpose xT) and W. Two dispatches.
//
// REGISTER PRESSURE (rounds 3-4 lesson): with 1024-thread blocks the right
// spot is __launch_bounds__(1024, 4): 4 waves/SIMD -> VGPR budget 128.
//   - round 3: min-waves=8 -> cap 64, allocator hit 32 -> ~1 GB/dispatch spill.
//   - round 4: no min-waves -> heuristic still chose 64 -> ~550 MB spill
//     (WRITE_SIZE 246 MB vs 128 KB legitimate).
// Unroll factor 4 (not 16) keeps the live float4 set inside 128 regs.

// ---- one-time transpose: xT[b][c][i][n] = x[b][n][c][i] ----
__global__ __launch_bounds__(1024) void k_transpose(
    const float* __restrict__ x, float* __restrict__ xT) {
  int b = blockIdx.x >> 4, c = blockIdx.x & 15;
  __shared__ __align__(16) float xsT[II][NN + 4];   // +4: f4-aligned padded rows
  int tid = threadIdx.x;
  {
    int n = tid >> 3, i4 = (tid & 7) * 4;
    float4 v = *(const float4*)(x + (((size_t)(b * NN + n)) * CC + c) * II + i4);
    xsT[i4 + 0][n] = v.x; xsT[i4 + 1][n] = v.y;
    xsT[i4 + 2][n] = v.z; xsT[i4 + 3][n] = v.w;
  }
  __syncthreads();
  {
    int i = tid >> 5, n4 = tid & 31;
    float4 v = *(const float4*)(&xsT[i][n4 * 4]);   // row stride 528 B, 16B-aligned
    ((float4*)(xT + ((size_t)(b * CC + c)) * II * NN))[tid] = v;
  }
}

// ---- the whole routing loop. Block per (b, o-pair). 1024 threads. ----
__global__ __launch_bounds__(1024, 4) void k_route(
    const float* __restrict__ xT, const float* __restrict__ W,
    float* __restrict__ out) {
  int bid = blockIdx.x;
  int b = bid & 31, o0 = (bid >> 5) * 2;      // o-pair {o0, o0+1}
  int tid = threadIdx.x;

  __shared__ __align__(16) float bijL[2][CC][NN];   // 16 KB routing logits
  __shared__ __align__(16) float coef[2][CC][NN];   // 16 KB softmax coefs
  __shared__ float cxs[2][CC][II];                  // 4 KB
  __shared__ float wv [2][CC][II];                  // 4 KB
  __shared__ float partA[2][CC][JJ];                // 4 KB
  __shared__ float vs[2][JJ];
  __shared__ float redM[CC][2];
  __shared__ float smx[2], srin[2];
  // total ~45 KB -> 2 blocks/CU (thread-capped), 32 waves/CU

  {  // bijL = 0 (first U adds it; matches reference b_ij=0 start)
    int o = tid >> 9, c = (tid >> 5) & 15, n4 = tid & 31;
    *(float4*)(&bijL[o][c][n4 * 4]) = make_float4(0.f, 0.f, 0.f, 0.f);
  }

  const float4* xTb = (const float4*)(xT + (size_t)b * CC * II * NN);
  // f4 index within b: c*1024 + i*32 + nf4

  for (int it = 0; it < 3; ++it) {
    // --- preC: coef[o][c][n] = softmax coefficient (uniform on iter 0) ---
    {
      int o = tid >> 9, c = (tid >> 5) & 15, n4 = tid & 31;
      float4 cf;
      if (it == 0) {
        float u = 1.0f / (float)MM;
        cf = make_float4(u, u, u, u);
      } else {
        float4 bb = *(const float4*)(&bijL[o][c][n4 * 4]);
        float m = smx[o], r = srin[o];
        cf.x = __expf(bb.x - m) * r; cf.y = __expf(bb.y - m) * r;
        cf.z = __expf(bb.z - m) * r; cf.w = __expf(bb.w - m) * r;
      }
      *(float4*)(&coef[o][c][n4 * 4]) = cf;
    }
    __syncthreads();

    // --- C: cxs[o][c][i] = sum_n coef[o][c][n] * xT[b][c][i][n] ---
    // wave = one c; lane (i, s-half of n); coef reads are 2-addr broadcasts.
    {
      int c = tid >> 6, l = tid & 63, i = l >> 1, s = l & 1;
      const float4* xr = xTb + c * (II * NN / 4) + i * (NN / 4) + s * 16;
      const float4* c0 = (const float4*)(&coef[0][c][s * 64]);
      const float4* c1 = (const float4*)(&coef[1][c][s * 64]);
      float a0 = 0.f, a1 = 0.f;
      #pragma unroll 4
      for (int q = 0; q < 16; ++q) {
        float4 xv = xr[q];
        float4 f0 = c0[q], f1 = c1[q];
        a0 += xv.x * f0.x + xv.y * f0.y + xv.z * f0.z + xv.w * f0.w;
        a1 += xv.x * f1.x + xv.y * f1.y + xv.z * f1.z + xv.w * f1.w;
      }
      a0 += __shfl_xor(a0, 1);           // combine n-halves (s-pair lanes)
      a1 += __shfl_xor(a1, 1);
      cxs[s][c][i] = (s == 0) ? a0 : a1; // lane s owns o=s
    }
    __syncthreads();

    // --- A: partA[o][c][j] = sum_i cxs[o][c][i] * W[c][o0+o][i][j] ---
    {
      int o = tid >> 9, c = (tid >> 5) & 15, j = tid & 31;
      const float* Wp = W + (((size_t)(c * OO + o0 + o)) * II) * JJ + j;
      float acc = 0.f;
      #pragma unroll 8
      for (int i = 0; i < II; ++i)
        acc += cxs[o][c][i] * Wp[i * JJ];   // cxs broadcast, W j-coalesced
      partA[o][c][j] = acc;
    }
    __syncthreads();

    // --- A-reduce + squash (final iter writes output) ---
    if (tid < 64) {
      int o = tid >> 5, j = tid & 31;
      float s = 0.f;
      #pragma unroll
      for (int c = 0; c < CC; ++c) s += partA[o][c][j];
      float msq = s * s;
      #pragma unroll
      for (int off = 16; off > 0; off >>= 1) msq += __shfl_xor(msq, off);
      float mag = sqrtf(msq) + EPS_;
      float a   = msq / (1.0f + msq);
      float vv  = a * s / mag;
      if (it == 2) {
        int row = b * OO + (o0 + o);
        out[(size_t)row * JJ + j] = vv;                // v_j: [B,1,O,J] flat
        if (j == 0) out[BB * OO * JJ + row] = a;       // a_j: [B,1,O,1] flat
      } else {
        vs[o][j] = vv;
      }
    }
    if (it == 2) break;                   // uniform exit
    __syncthreads();

    // --- Wv: wv[o][c][i] = sum_j W[c][o0+o][i][j] * vs[o][j] ---
    {
      int o = tid >> 9, c = (tid >> 5) & 15, i = tid & 31;
      const float4* Wr = (const float4*)(W + (((size_t)(c * OO + o0 + o)) * II + i) * JJ);
      float acc = 0.f;
      #pragma unroll 4
      for (int q = 0; q < 8; ++q) {
        float4 w4 = Wr[q];
        acc += w4.x * vs[o][q*4+0] + w4.y * vs[o][q*4+1]
             + w4.z * vs[o][q*4+2] + w4.w * vs[o][q*4+3];
      }
      wv[o][c][i] = acc;
    }
    __syncthreads();

    // --- U: bijL[o][c][n] += sum_i xT[b][c][i][n]*wv[o][c][i]; then stats ---
    // lane (c, n4, s-half of i); xT f4 reads shared by BOTH o's; 512B runs.
    {
      int c = tid >> 6, n4 = (tid >> 1) & 31, s = tid & 1;
      float4 ac0 = make_float4(0.f,0.f,0.f,0.f);
      float4 ac1 = make_float4(0.f,0.f,0.f,0.f);
      #pragma unroll 4
      for (int q = 0; q < 16; ++q) {
        int i = s * 16 + q;
        float4 xv = xTb[c * (II * NN / 4) + i * (NN / 4) + n4];
        float w0 = wv[0][c][i], w1 = wv[1][c][i];   // broadcasts
        ac0.x += xv.x * w0; ac0.y += xv.y * w0; ac0.z += xv.z * w0; ac0.w += xv.w * w0;
        ac1.x += xv.x * w1; ac1.y += xv.y * w1; ac1.z += xv.z * w1; ac1.w += xv.w * w1;
      }
      // combine i-halves across the s-pair
      ac0.x += __shfl_xor(ac0.x, 1); ac0.y += __shfl_xor(ac0.y, 1);
      ac0.z += __shfl_xor(ac0.z, 1); ac0.w += __shfl_xor(ac0.w, 1);
      ac1.x += __shfl_xor(ac1.x, 1); ac1.y += __shfl_xor(ac1.y, 1);
      ac1.z += __shfl_xor(ac1.z, 1); ac1.w += __shfl_xor(ac1.w, 1);
      float4 r = (s == 0) ? ac0 : ac1;              // lane s owns o=s
      float4 bb = *(const float4*)(&bijL[s][c][n4 * 4]);
      r.x += bb.x; r.y += bb.y; r.z += bb.z; r.w += bb.w;
      *(float4*)(&bijL[s][c][n4 * 4]) = r;

      // softmax stats for the NEXT iteration (row fully block-owned)
      float m4 = fmaxf(fmaxf(r.x, r.y), fmaxf(r.z, r.w));
      #pragma unroll
      for (int off = 2; off <= 32; off <<= 1)       // parity-preserving reduce
        m4 = fmaxf(m4, __shfl_xor(m4, off));
      if ((tid & 63) <= 1) redM[c][s] = m4;         // lane 0: o=0, lane 1: o=1
      __syncthreads();
      if (tid < 2) {
        float m = redM[0][tid];
        #pragma unroll
        for (int w2 = 1; w2 < CC; ++w2) m = fmaxf(m, redM[w2][tid]);
        smx[tid] = m;
      }
      __syncthreads();
      float mo = smx[s];
      float e = __expf(r.x - mo) + __expf(r.y - mo)
              + __expf(r.z - mo) + __expf(r.w - mo);
      #pragma unroll
      for (int off = 2; off <= 32; off <<= 1) e += __shfl_xor(e, off);
      if ((tid & 63) <= 1) redM[c][s] = e;
      __syncthreads();
      if (tid < 2) {
        float ss = 0.f;
        #pragma unroll
        for (int w2 = 0; w2 < CC; ++w2) ss += redM[w2][tid];
        srin[tid] = 1.0f / ss;
      }
    }
    __syncthreads();
  }
}

extern "C" void kernel_launch(void* const* d_in, const int* in_sizes, int n_in,
                              void* d_out, int out_size, void* d_ws, size_t ws_size,
                              hipStream_t stream) {
  const float* x = (const float*)d_in[0];   // [B,N,C,I]
  const float* W = (const float*)d_in[1];   // [C,O,I,J]
  (void)in_sizes; (void)n_in;               // d_in[2] = number_of_nodes (fixed 128)
  float* out = (float*)d_out; (void)out_size;

  float* xT = (float*)d_ws;                 // 2,097,152 floats (8 MB)
  (void)ws_size;

  k_transpose<<<BB * CC, 1024, 0, stream>>>(x, xT);
  k_route<<<BB * (OO / 2), 1024, 0, stream>>>(xT, W, out);
}

// Round 6
// 127.088 us; speedup vs baseline: 3.5592x; 1.2423x over previous
//
#include <hip/hip_runtime.h>
#include <math.h>

// Problem constants (fixed by the reference):
#define BB 32     // batch
#define NN 128    // nodes
#define CC 16     // in_ch
#define OO 32     // out_ch
#define II 32     // in_dim
#define JJ 32     // out_dim
#define MM (NN*CC)  // 2048 input capsules per (b, out_ch)
static constexpr float EPS_ = 1e-11f;

// The routing recurrence is INDEPENDENT per (b,o): one block owns a
// (b, o-pair) end-to-end; bij/coef/cx/v/wv/stats all live in LDS. Only
// global arrays: x (via one-time transposes) and W. Two dispatches.
//
// REGISTER PRESSURE (rounds 3-4): __launch_bounds__(1024, 4) -> VGPR 128.
// Forcing 8 waves/SIMD (or letting the heuristic pick 64 VGPRs) spills
// ~0.5-1 KB/thread -> hundreds of MB of scratch HBM traffic.
//
// COALESCING (round 5): phase C with i-major xT had lanes at stride 256 B
// reading 16 B each -> 64 distinct cache lines/instr, 25% line use, L1
// thrash (512 KB working set vs 32 KB L1) -> ~4x L2 over-read. Fix: keep
// i-major xT for phase U (already contiguous) and add an n-major layout
// x4T[b][c][nf4][i] (float4 = 4 consecutive n at one i) so phase C reads
// are lane-contiguous 1 KB/instr and the n-reduction is lane-local.

// ---- one-time transpose: xT[b][c][i][n] and x4T[b][c][nf4][i] ----
__global__ __launch_bounds__(1024) void k_transpose(
    const float* __restrict__ x, float* __restrict__ xT,
    float* __restrict__ x4T) {
  int b = blockIdx.x >> 4, c = blockIdx.x & 15;
  __shared__ __align__(16) float xsT[II][NN + 4];   // +4: f4-aligned padded rows
  int tid = threadIdx.x;
  {
    int n = tid >> 3, i4 = (tid & 7) * 4;
    float4 v = *(const float4*)(x + (((size_t)(b * NN + n)) * CC + c) * II + i4);
    xsT[i4 + 0][n] = v.x; xsT[i4 + 1][n] = v.y;
    xsT[i4 + 2][n] = v.z; xsT[i4 + 3][n] = v.w;
  }
  __syncthreads();
  {
    int i = tid >> 5, n4 = tid & 31;
    float4 v = *(const float4*)(&xsT[i][n4 * 4]);   // row stride 528 B, 16B-aligned
    ((float4*)(xT + ((size_t)(b * CC + c)) * II * NN))[tid] = v;
  }
  {
    int nf4 = tid >> 5, i = tid & 31;               // f4 idx = nf4*32 + i = tid
    float4 v = make_float4(xsT[i][nf4 * 4 + 0], xsT[i][nf4 * 4 + 1],
                           xsT[i][nf4 * 4 + 2], xsT[i][nf4 * 4 + 3]);
    ((float4*)(x4T + ((size_t)(b * CC + c)) * II * NN))[tid] = v;
  }
}

// ---- the whole routing loop. Block per (b, o-pair). 1024 threads. ----
__global__ __launch_bounds__(1024, 4) void k_route(
    const float* __restrict__ xT, const float* __restrict__ x4T,
    const float* __restrict__ W, float* __restrict__ out) {
  int bid = blockIdx.x;
  int b = bid & 31, o0 = (bid >> 5) * 2;      // o-pair {o0, o0+1}
  int tid = threadIdx.x;

  __shared__ __align__(16) float bijL[2][CC][NN];   // 16 KB routing logits
  __shared__ __align__(16) float coef[2][CC][NN];   // 16 KB softmax coefs
  __shared__ float cxs[2][CC][II];                  // 4 KB
  __shared__ float wv [2][CC][II];                  // 4 KB
  __shared__ float partA[2][CC][JJ];                // 4 KB
  __shared__ float vs[2][JJ];
  __shared__ float redM[CC][2];
  __shared__ float smx[2], srin[2];
  // total ~45 KB -> 2 blocks/CU (thread-capped), 32 waves/CU

  {  // bijL = 0 (first U adds it; matches reference b_ij=0 start)
    int o = tid >> 9, c = (tid >> 5) & 15, n4 = tid & 31;
    *(float4*)(&bijL[o][c][n4 * 4]) = make_float4(0.f, 0.f, 0.f, 0.f);
  }

  const float4* xTb  = (const float4*)(xT  + (size_t)b * CC * II * NN);
  const float4* x4Tb = (const float4*)(x4T + (size_t)b * CC * II * NN);

  for (int it = 0; it < 3; ++it) {
    // --- preC: coef[o][c][n] = softmax coefficient (uniform on iter 0) ---
    {
      int o = tid >> 9, c = (tid >> 5) & 15, n4 = tid & 31;
      float4 cf;
      if (it == 0) {
        float u = 1.0f / (float)MM;
        cf = make_float4(u, u, u, u);
      } else {
        float4 bb = *(const float4*)(&bijL[o][c][n4 * 4]);
        float m = smx[o], r = srin[o];
        cf.x = __expf(bb.x - m) * r; cf.y = __expf(bb.y - m) * r;
        cf.z = __expf(bb.z - m) * r; cf.w = __expf(bb.w - m) * r;
      }
      *(float4*)(&coef[o][c][n4 * 4]) = cf;
    }
    __syncthreads();

    // --- C: cxs[o][c][i] = sum_n coef[o][c][n] * x[c,i,n] via x4T ---
    // wave = one c; lane l: i = l&31, nh = l>>5. x4T reads lane-contiguous
    // (1 KB/instr); coef reads are 2-address LDS broadcasts; n-reduction
    // is lane-local + one shfl_xor(32) pair.
    {
      int c = tid >> 6, l = tid & 63, i = l & 31, nh = l >> 5;
      const float4* xr = x4Tb + c * (II * NN / 4) + l;
      float a0 = 0.f, a1 = 0.f;
      #pragma unroll 4
      for (int q = 0; q < 16; ++q) {
        float4 xv = xr[q * 64];                      // f4 idx q*64 + l
        int nf = 2 * q + nh;
        float4 f0 = *(const float4*)(&coef[0][c][nf * 4]);
        float4 f1 = *(const float4*)(&coef[1][c][nf * 4]);
        a0 += xv.x * f0.x + xv.y * f0.y + xv.z * f0.z + xv.w * f0.w;
        a1 += xv.x * f1.x + xv.y * f1.y + xv.z * f1.z + xv.w * f1.w;
      }
      a0 += __shfl_xor(a0, 32);                      // combine nh halves
      a1 += __shfl_xor(a1, 32);
      if (nh == 0) cxs[0][c][i] = a0;
      else         cxs[1][c][i] = a1;
    }
    __syncthreads();

    // --- A: partA[o][c][j] = sum_i cxs[o][c][i] * W[c][o0+o][i][j] ---
    {
      int o = tid >> 9, c = (tid >> 5) & 15, j = tid & 31;
      const float* Wp = W + (((size_t)(c * OO + o0 + o)) * II) * JJ + j;
      float acc = 0.f;
      #pragma unroll 8
      for (int i = 0; i < II; ++i)
        acc += cxs[o][c][i] * Wp[i * JJ];   // cxs broadcast, W j-coalesced
      partA[o][c][j] = acc;
    }
    __syncthreads();

    // --- A-reduce + squash (final iter writes output) ---
    if (tid < 64) {
      int o = tid >> 5, j = tid & 31;
      float s = 0.f;
      #pragma unroll
      for (int c = 0; c < CC; ++c) s += partA[o][c][j];
      float msq = s * s;
      #pragma unroll
      for (int off = 16; off > 0; off >>= 1) msq += __shfl_xor(msq, off);
      float mag = sqrtf(msq) + EPS_;
      float a   = msq / (1.0f + msq);
      float vv  = a * s / mag;
      if (it == 2) {
        int row = b * OO + (o0 + o);
        out[(size_t)row * JJ + j] = vv;                // v_j: [B,1,O,J] flat
        if (j == 0) out[BB * OO * JJ + row] = a;       // a_j: [B,1,O,1] flat
      } else {
        vs[o][j] = vv;
      }
    }
    if (it == 2) break;                   // uniform exit
    __syncthreads();

    // --- Wv: wv[o][c][i] = sum_j W[c][o0+o][i][j] * vs[o][j] ---
    {
      int o = tid >> 9, c = (tid >> 5) & 15, i = tid & 31;
      const float4* Wr = (const float4*)(W + (((size_t)(c * OO + o0 + o)) * II + i) * JJ);
      float acc = 0.f;
      #pragma unroll 4
      for (int q = 0; q < 8; ++q) {
        float4 w4 = Wr[q];
        acc += w4.x * vs[o][q*4+0] + w4.y * vs[o][q*4+1]
             + w4.z * vs[o][q*4+2] + w4.w * vs[o][q*4+3];
      }
      wv[o][c][i] = acc;
    }
    __syncthreads();

    // --- U: bijL[o][c][n] += sum_i xT[b][c][i][n]*wv[o][c][i]; then stats ---
    // lane (c, n4, s-half of i); xT f4 reads: two full 512B runs/instr.
    {
      int c = tid >> 6, n4 = (tid >> 1) & 31, s = tid & 1;
      float4 ac0 = make_float4(0.f,0.f,0.f,0.f);
      float4 ac1 = make_float4(0.f,0.f,0.f,0.f);
      #pragma unroll 4
      for (int q = 0; q < 16; ++q) {
        int i = s * 16 + q;
        float4 xv = xTb[c * (II * NN / 4) + i * (NN / 4) + n4];
        float w0 = wv[0][c][i], w1 = wv[1][c][i];   // broadcasts
        ac0.x += xv.x * w0; ac0.y += xv.y * w0; ac0.z += xv.z * w0; ac0.w += xv.w * w0;
        ac1.x += xv.x * w1; ac1.y += xv.y * w1; ac1.z += xv.z * w1; ac1.w += xv.w * w1;
      }
      // combine i-halves across the s-pair
      ac0.x += __shfl_xor(ac0.x, 1); ac0.y += __shfl_xor(ac0.y, 1);
      ac0.z += __shfl_xor(ac0.z, 1); ac0.w += __shfl_xor(ac0.w, 1);
      ac1.x += __shfl_xor(ac1.x, 1); ac1.y += __shfl_xor(ac1.y, 1);
      ac1.z += __shfl_xor(ac1.z, 1); ac1.w += __shfl_xor(ac1.w, 1);
      float4 r = (s == 0) ? ac0 : ac1;              // lane s owns o=s
      float4 bb = *(const float4*)(&bijL[s][c][n4 * 4]);
      r.x += bb.x; r.y += bb.y; r.z += bb.z; r.w += bb.w;
      *(float4*)(&bijL[s][c][n4 * 4]) = r;

      // softmax stats for the NEXT iteration (row fully block-owned)
      float m4 = fmaxf(fmaxf(r.x, r.y), fmaxf(r.z, r.w));
      #pragma unroll
      for (int off = 2; off <= 32; off <<= 1)       // parity-preserving reduce
        m4 = fmaxf(m4, __shfl_xor(m4, off));
      if ((tid & 63) <= 1) redM[c][s] = m4;         // lane 0: o=0, lane 1: o=1
      __syncthreads();
      if (tid < 2) {
        float m = redM[0][tid];
        #pragma unroll
        for (int w2 = 1; w2 < CC; ++w2) m = fmaxf(m, redM[w2][tid]);
        smx[tid] = m;
      }
      __syncthreads();
      float mo = smx[s];
      float e = __expf(r.x - mo) + __expf(r.y - mo)
              + __expf(r.z - mo) + __expf(r.w - mo);
      #pragma unroll
      for (int off = 2; off <= 32; off <<= 1) e += __shfl_xor(e, off);
      if ((tid & 63) <= 1) redM[c][s] = e;
      __syncthreads();
      if (tid < 2) {
        float ss = 0.f;
        #pragma unroll
        for (int w2 = 0; w2 < CC; ++w2) ss += redM[w2][tid];
        srin[tid] = 1.0f / ss;
      }
    }
    __syncthreads();
  }
}

extern "C" void kernel_launch(void* const* d_in, const int* in_sizes, int n_in,
                              void* d_out, int out_size, void* d_ws, size_t ws_size,
                              hipStream_t stream) {
  const float* x = (const float*)d_in[0];   // [B,N,C,I]
  const float* W = (const float*)d_in[1];   // [C,O,I,J]
  (void)in_sizes; (void)n_in;               // d_in[2] = number_of_nodes (fixed 128)
  float* out = (float*)d_out; (void)out_size;

  float* xT  = (float*)d_ws;                // 2,097,152 floats (8 MB), i-major
  float* x4T = xT + (size_t)BB * CC * II * NN;   // 8 MB, n-major
  (void)ws_size;  // total 16 MB

  k_transpose<<<BB * CC, 1024, 0, stream>>>(x, xT, x4T);
  k_route<<<BB * (OO / 2), 1024, 0, stream>>>(xT, x4T, W, out);
}

// Round 7
// 122.874 us; speedup vs baseline: 3.6812x; 1.0343x over previous
//
#include <hip/hip_runtime.h>
#include <math.h>

// Problem constants (fixed by the reference):
#define BB 32     // batch
#define NN 128    // nodes
#define CC 16     // in_ch
#define OO 32     // out_ch
#define II 32     // in_dim
#define JJ 32     // out_dim
#define MM (NN*CC)  // 2048 input capsules per (b, out_ch)
static constexpr float EPS_ = 1e-11f;

// One block owns a (b, o-pair) end-to-end; bij/coef/cx/v/wv live in LDS.
// Round-6 lesson: VALU-issue model matched VALUBusy exactly -> the 75%
// stall is L2 latency + barriers. All global operands are ITERATION-
// INVARIANT, so this round:
//   * W cached in REGISTERS per thread (A-column 32 f32 + Wv-row 8 f4 =
//     64 VGPR, loaded once) -> phases A and Wv are pure LDS+FMA, W L2
//     traffic drops from 128 MB/iter to one-time 64 MB.
//   * preC phase deleted: U's tail already holds the new bij values and
//     the exp() results in registers -> writes coef directly.
//   * stats reduction: every thread reduces the 16 wave-partials locally
//     (redundant but barrier-light): 5 barriers/iter -> 3 in U's tail.
// VGPR budget: __launch_bounds__(1024,4) -> cap 128. 52 (round 6) + 64 W
// regs ~= 116. If WRITE_SIZE blows up next round, the W cache spilled.

// ---- one-time transpose: xT[b][c][i][n] and x4T[b][c][nf4][i] ----
__global__ __launch_bounds__(1024) void k_transpose(
    const float* __restrict__ x, float* __restrict__ xT,
    float* __restrict__ x4T) {
  int b = blockIdx.x >> 4, c = blockIdx.x & 15;
  __shared__ __align__(16) float xsT[II][NN + 4];   // +4: f4-aligned padded rows
  int tid = threadIdx.x;
  {
    int n = tid >> 3, i4 = (tid & 7) * 4;
    float4 v = *(const float4*)(x + (((size_t)(b * NN + n)) * CC + c) * II + i4);
    xsT[i4 + 0][n] = v.x; xsT[i4 + 1][n] = v.y;
    xsT[i4 + 2][n] = v.z; xsT[i4 + 3][n] = v.w;
  }
  __syncthreads();
  {
    int i = tid >> 5, n4 = tid & 31;
    float4 v = *(const float4*)(&xsT[i][n4 * 4]);   // row stride 528 B, 16B-aligned
    ((float4*)(xT + ((size_t)(b * CC + c)) * II * NN))[tid] = v;
  }
  {
    int nf4 = tid >> 5, i = tid & 31;               // f4 idx = nf4*32 + i = tid
    float4 v = make_float4(xsT[i][nf4 * 4 + 0], xsT[i][nf4 * 4 + 1],
                           xsT[i][nf4 * 4 + 2], xsT[i][nf4 * 4 + 3]);
    ((float4*)(x4T + ((size_t)(b * CC + c)) * II * NN))[tid] = v;
  }
}

// ---- the whole routing loop. Block per (b, o-pair). 1024 threads. ----
__global__ __launch_bounds__(1024, 4) void k_route(
    const float* __restrict__ xT, const float* __restrict__ x4T,
    const float* __restrict__ W, float* __restrict__ out) {
  int bid = blockIdx.x;
  int b = bid & 31, o0 = (bid >> 5) * 2;      // o-pair {o0, o0+1}
  int tid = threadIdx.x;

  __shared__ __align__(16) float bijL[2][CC][NN];   // 16 KB routing logits
  __shared__ __align__(16) float coef[2][CC][NN];   // 16 KB softmax coefs
  __shared__ float cxs[2][CC][II];                  // 4 KB
  __shared__ float wv [2][CC][II];                  // 4 KB
  __shared__ float partA[2][CC][JJ];                // 4 KB
  __shared__ float vs[2][JJ];
  __shared__ float redM[CC][2], redE[CC][2];
  // total ~44.5 KB -> 2 blocks/CU (thread-capped), 32 waves/CU

  {  // init: bijL = 0, coef = uniform (iter-0 softmax of zeros)
    int o = tid >> 9, c = (tid >> 5) & 15, n4 = tid & 31;
    *(float4*)(&bijL[o][c][n4 * 4]) = make_float4(0.f, 0.f, 0.f, 0.f);
    float u = 1.0f / (float)MM;
    *(float4*)(&coef[o][c][n4 * 4]) = make_float4(u, u, u, u);
  }

  // ---- prologue: W into registers (iteration-invariant) ----
  float wA[II];       // A-phase column W[c][o0+o][i][j], i=0..31 (this thread's o,c,j)
  {
    int o = tid >> 9, c = (tid >> 5) & 15, j = tid & 31;
    const float* Wp = W + (((size_t)(c * OO + o0 + o)) * II) * JJ + j;
    #pragma unroll
    for (int i = 0; i < II; ++i) wA[i] = Wp[i * JJ];   // j-coalesced
  }
  float4 wW[8];       // Wv-phase row W[c][o0+o][i][0..31] (this thread's o,c,i)
  {
    int o = tid >> 9, c = (tid >> 5) & 15, i = tid & 31;
    const float4* Wr = (const float4*)(W + (((size_t)(c * OO + o0 + o)) * II + i) * JJ);
    #pragma unroll
    for (int q = 0; q < 8; ++q) wW[q] = Wr[q];          // one-time, latency hidden
  }

  const float4* xTb  = (const float4*)(xT  + (size_t)b * CC * II * NN);
  const float4* x4Tb = (const float4*)(x4T + (size_t)b * CC * II * NN);
  __syncthreads();

  for (int it = 0; it < 3; ++it) {
    // --- C: cxs[o][c][i] = sum_n coef[o][c][n] * x[c,i,n] via x4T ---
    // wave = one c; lane l: i = l&31, nh = l>>5; x4T lane-contiguous 1KB/instr.
    {
      int c = tid >> 6, l = tid & 63, i = l & 31, nh = l >> 5;
      const float4* xr = x4Tb + c * (II * NN / 4) + l;
      float a0 = 0.f, a1 = 0.f;
      #pragma unroll 4
      for (int q = 0; q < 16; ++q) {
        float4 xv = xr[q * 64];                      // f4 idx q*64 + l
        int nf = 2 * q + nh;
        float4 f0 = *(const float4*)(&coef[0][c][nf * 4]);
        float4 f1 = *(const float4*)(&coef[1][c][nf * 4]);
        a0 += xv.x * f0.x + xv.y * f0.y + xv.z * f0.z + xv.w * f0.w;
        a1 += xv.x * f1.x + xv.y * f1.y + xv.z * f1.z + xv.w * f1.w;
      }
      a0 += __shfl_xor(a0, 32);                      // combine nh halves
      a1 += __shfl_xor(a1, 32);
      if (nh == 0) cxs[0][c][i] = a0;
      else         cxs[1][c][i] = a1;
    }
    __syncthreads();

    // --- A: partA[o][c][j] = sum_i cxs[o][c][i] * wA[i]  (pure LDS+FMA) ---
    {
      int o = tid >> 9, c = (tid >> 5) & 15, j = tid & 31;
      float acc = 0.f;
      #pragma unroll
      for (int i = 0; i < II; ++i)
        acc += cxs[o][c][i] * wA[i];                 // cxs broadcast
      partA[o][c][j] = acc;
    }
    __syncthreads();

    // --- A-reduce + squash (final iter writes output) ---
    if (tid < 64) {
      int o = tid >> 5, j = tid & 31;
      float s = 0.f;
      #pragma unroll
      for (int c = 0; c < CC; ++c) s += partA[o][c][j];
      float msq = s * s;
      #pragma unroll
      for (int off = 16; off > 0; off >>= 1) msq += __shfl_xor(msq, off);
      float mag = sqrtf(msq) + EPS_;
      float a   = msq / (1.0f + msq);
      float vv  = a * s / mag;
      if (it == 2) {
        int row = b * OO + (o0 + o);
        out[(size_t)row * JJ + j] = vv;                // v_j: [B,1,O,J] flat
        if (j == 0) out[BB * OO * JJ + row] = a;       // a_j: [B,1,O,1] flat
      } else {
        vs[o][j] = vv;
      }
    }
    if (it == 2) break;                   // uniform exit
    __syncthreads();

    // --- Wv: wv[o][c][i] = sum_j wW[j4] . vs[o][j]  (pure LDS+FMA) ---
    {
      int o = tid >> 9, c = (tid >> 5) & 15, i = tid & 31;
      float acc = 0.f;
      #pragma unroll
      for (int q = 0; q < 8; ++q) {
        acc += wW[q].x * vs[o][q*4+0] + wW[q].y * vs[o][q*4+1]
             + wW[q].z * vs[o][q*4+2] + wW[q].w * vs[o][q*4+3];
      }
      wv[o][c][i] = acc;
    }
    __syncthreads();

    // --- U: bijL += x.wv; softmax stats + coef for NEXT iter, fused ---
    // lane (c, n4, s-half of i); xT f4 reads: full 512B runs.
    {
      int c = tid >> 6, n4 = (tid >> 1) & 31, s = tid & 1;
      float4 ac0 = make_float4(0.f,0.f,0.f,0.f);
      float4 ac1 = make_float4(0.f,0.f,0.f,0.f);
      #pragma unroll 4
      for (int q = 0; q < 16; ++q) {
        int i = s * 16 + q;
        float4 xv = xTb[c * (II * NN / 4) + i * (NN / 4) + n4];
        float w0 = wv[0][c][i], w1 = wv[1][c][i];   // broadcasts
        ac0.x += xv.x * w0; ac0.y += xv.y * w0; ac0.z += xv.z * w0; ac0.w += xv.w * w0;
        ac1.x += xv.x * w1; ac1.y += xv.y * w1; ac1.z += xv.z * w1; ac1.w += xv.w * w1;
      }
      // combine i-halves across the s-pair
      ac0.x += __shfl_xor(ac0.x, 1); ac0.y += __shfl_xor(ac0.y, 1);
      ac0.z += __shfl_xor(ac0.z, 1); ac0.w += __shfl_xor(ac0.w, 1);
      ac1.x += __shfl_xor(ac1.x, 1); ac1.y += __shfl_xor(ac1.y, 1);
      ac1.z += __shfl_xor(ac1.z, 1); ac1.w += __shfl_xor(ac1.w, 1);
      float4 r = (s == 0) ? ac0 : ac1;              // lane s owns o=s
      float4 bb = *(const float4*)(&bijL[s][c][n4 * 4]);
      r.x += bb.x; r.y += bb.y; r.z += bb.z; r.w += bb.w;
      *(float4*)(&bijL[s][c][n4 * 4]) = r;

      // per-wave max partials (parity-preserving: offsets 2..32)
      float m4 = fmaxf(fmaxf(r.x, r.y), fmaxf(r.z, r.w));
      #pragma unroll
      for (int off = 2; off <= 32; off <<= 1) m4 = fmaxf(m4, __shfl_xor(m4, off));
      int wave = tid >> 6;
      if ((tid & 63) <= 1) redM[wave][s] = m4;      // lane 0: o=0, lane 1: o=1
      __syncthreads();
      float mo = redM[0][s];                        // every thread reduces locally
      #pragma unroll
      for (int w2 = 1; w2 < CC; ++w2) mo = fmaxf(mo, redM[w2][s]);
      float ex = __expf(r.x - mo), ey = __expf(r.y - mo),
            ez = __expf(r.z - mo), ew = __expf(r.w - mo);
      float e = ex + ey + ez + ew;
      #pragma unroll
      for (int off = 2; off <= 32; off <<= 1) e += __shfl_xor(e, off);
      if ((tid & 63) <= 1) redE[wave][s] = e;
      __syncthreads();
      float ss = redE[0][s];
      #pragma unroll
      for (int w2 = 1; w2 < CC; ++w2) ss += redE[w2][s];
      float rin = 1.0f / ss;
      // coef for the next iteration: reuse the exp values already computed
      *(float4*)(&coef[s][c][n4 * 4]) =
          make_float4(ex * rin, ey * rin, ez * rin, ew * rin);
    }
    __syncthreads();
  }
}

extern "C" void kernel_launch(void* const* d_in, const int* in_sizes, int n_in,
                              void* d_out, int out_size, void* d_ws, size_t ws_size,
                              hipStream_t stream) {
  const float* x = (const float*)d_in[0];   // [B,N,C,I]
  const float* W = (const float*)d_in[1];   // [C,O,I,J]
  (void)in_sizes; (void)n_in;               // d_in[2] = number_of_nodes (fixed 128)
  float* out = (float*)d_out; (void)out_size;

  float* xT  = (float*)d_ws;                // 2,097,152 floats (8 MB), i-major
  float* x4T = xT + (size_t)BB * CC * II * NN;   // 8 MB, n-major
  (void)ws_size;  // total 16 MB

  k_transpose<<<BB * CC, 1024, 0, stream>>>(x, xT, x4T);
  k_route<<<BB * (OO / 2), 1024, 0, stream>>>(xT, x4T, W, out);
}

// Round 8
// 119.226 us; speedup vs baseline: 3.7938x; 1.0306x over previous
//
#include <hip/hip_runtime.h>
#include <math.h>

// Problem constants (fixed by the reference):
#define BB 32     // batch
#define NN 128    // nodes
#define CC 16     // in_ch
#define OO 32     // out_ch
#define II 32     // in_dim
#define JJ 32     // out_dim
#define MM (NN*CC)  // 2048 input capsules per (b, out_ch)
static constexpr float EPS_ = 1e-11f;

// One block owns a (b, o-pair) end-to-end; bij/coef/cx/v/wv live in LDS.
//
// Round-7 lesson: W-in-registers never materialized (VGPR=64 < cache size;
// compiler re-read from L2) and x/W are L2-resident anyway -> the cost is
// per-iteration L2 LATENCY in the x-streaming phases, not traffic.
//
// This round: x is REGISTER-RESIDENT, loaded once. Thread (c,n4,s) holds
// xv[q] = x(b, c, i=s*16+q, n=n4*4..+3), q=0..15 (64 VGPR). U consumes it
// directly (same indexing as round 7). C computes 16 i-partials over the
// thread's 4 n's, then reduce-scatters across the 32 n4-lanes
// (shfl_xor d=2,4,8,16 halving slots, then d=32 allreduce): ~130 VALU ops
// replace 16 L2 loads/thread/iter. ZERO global loads inside the loop
// except the small W reads in A/Wv (L2-hot, iteration-invariant addrs).
// VGPR budget: __launch_bounds__(1024,4) -> cap 128; xv(64)+partials(32)
// +misc ~ 110. Spill tripwire: WRITE_SIZE must stay ~134 KB.

// ---- one-time transpose: xT[b][c][i][n] = x[b][n][c][i] ----
__global__ __launch_bounds__(1024) void k_transpose(
    const float* __restrict__ x, float* __restrict__ xT) {
  int b = blockIdx.x >> 4, c = blockIdx.x & 15;
  __shared__ __align__(16) float xsT[II][NN + 4];   // +4: f4-aligned padded rows
  int tid = threadIdx.x;
  {
    int n = tid >> 3, i4 = (tid & 7) * 4;
    float4 v = *(const float4*)(x + (((size_t)(b * NN + n)) * CC + c) * II + i4);
    xsT[i4 + 0][n] = v.x; xsT[i4 + 1][n] = v.y;
    xsT[i4 + 2][n] = v.z; xsT[i4 + 3][n] = v.w;
  }
  __syncthreads();
  {
    int i = tid >> 5, n4 = tid & 31;
    float4 v = *(const float4*)(&xsT[i][n4 * 4]);   // row stride 528 B, 16B-aligned
    ((float4*)(xT + ((size_t)(b * CC + c)) * II * NN))[tid] = v;
  }
}

// ---- the whole routing loop. Block per (b, o-pair). 1024 threads. ----
__global__ __launch_bounds__(1024, 4) void k_route(
    const float* __restrict__ xT, const float* __restrict__ W,
    float* __restrict__ out) {
  int bid = blockIdx.x;
  int b = bid & 31, o0 = (bid >> 5) * 2;      // o-pair {o0, o0+1}
  int tid = threadIdx.x;

  __shared__ __align__(16) float bijL[2][CC][NN];   // 16 KB routing logits
  __shared__ __align__(16) float coef[2][CC][NN];   // 16 KB softmax coefs
  __shared__ float cxs[2][CC][II];                  // 4 KB
  __shared__ float wv [2][CC][II];                  // 4 KB
  __shared__ float partA[2][CC][JJ];                // 4 KB
  __shared__ float vs[2][JJ];
  __shared__ float redM[CC][2], redE[CC][2];
  // total ~44.5 KB -> 2 blocks/CU (thread-capped), 32 waves/CU

  // x -> registers (once): thread (c, n4, s) owns i=s*16..s*16+15, n=n4*4..+3
  int l = tid & 63;
  int c = tid >> 6, n4 = l >> 1, s = l & 1;
  const float4* xTb = (const float4*)(xT + (size_t)b * CC * II * NN);
  const float4* xp  = xTb + c * (II * NN / 4) + (s * 16) * (NN / 4) + n4;
  float4 xv[16];
  #pragma unroll
  for (int q = 0; q < 16; ++q) xv[q] = xp[q * (NN / 4)];  // 512B runs, coalesced

  {  // init: bijL = 0, coef = uniform (iter-0 softmax of zeros)
    int o = tid >> 9, ci = (tid >> 5) & 15, m4i = tid & 31;
    *(float4*)(&bijL[o][ci][m4i * 4]) = make_float4(0.f, 0.f, 0.f, 0.f);
    float u = 1.0f / (float)MM;
    *(float4*)(&coef[o][ci][m4i * 4]) = make_float4(u, u, u, u);
  }
  __syncthreads();

  for (int it = 0; it < 3; ++it) {
    // --- C: cxs[o][c][i] = sum_n coef[o][c][n]*x(c,n,i), all from regs/LDS ---
    {
      float4 cf0 = *(const float4*)(&coef[0][c][n4 * 4]);
      float4 cf1 = *(const float4*)(&coef[1][c][n4 * 4]);
      float p0[16], p1[16];
      #pragma unroll
      for (int q = 0; q < 16; ++q) {   // partials over this lane's 4 n's
        p0[q] = xv[q].x*cf0.x + xv[q].y*cf0.y + xv[q].z*cf0.z + xv[q].w*cf0.w;
        p1[q] = xv[q].x*cf1.x + xv[q].y*cf1.y + xv[q].z*cf1.z + xv[q].w*cf1.w;
      }
      // reduce-scatter over n4 bits 0..3 (lane bits 1..4), slots 16->1
      bool u2 = (l >> 1) & 1, u4 = (l >> 2) & 1, u8 = (l >> 3) & 1, u16 = (l >> 4) & 1;
      #pragma unroll
      for (int k = 0; k < 8; ++k) {    // d=2: keep half by u2
        float s0 = u2 ? p0[k] : p0[k+8], s1 = u2 ? p1[k] : p1[k+8];
        float r0 = __shfl_xor(s0, 2),   r1 = __shfl_xor(s1, 2);
        p0[k] = (u2 ? p0[k+8] : p0[k]) + r0;
        p1[k] = (u2 ? p1[k+8] : p1[k]) + r1;
      }
      #pragma unroll
      for (int k = 0; k < 4; ++k) {    // d=4
        float s0 = u4 ? p0[k] : p0[k+4], s1 = u4 ? p1[k] : p1[k+4];
        float r0 = __shfl_xor(s0, 4),   r1 = __shfl_xor(s1, 4);
        p0[k] = (u4 ? p0[k+4] : p0[k]) + r0;
        p1[k] = (u4 ? p1[k+4] : p1[k]) + r1;
      }
      #pragma unroll
      for (int k = 0; k < 2; ++k) {    // d=8
        float s0 = u8 ? p0[k] : p0[k+2], s1 = u8 ? p1[k] : p1[k+2];
        float r0 = __shfl_xor(s0, 8),   r1 = __shfl_xor(s1, 8);
        p0[k] = (u8 ? p0[k+2] : p0[k]) + r0;
        p1[k] = (u8 ? p1[k+2] : p1[k]) + r1;
      }
      {                                 // d=16
        float s0 = u16 ? p0[0] : p0[1], s1 = u16 ? p1[0] : p1[1];
        float r0 = __shfl_xor(s0, 16),  r1 = __shfl_xor(s1, 16);
        p0[0] = (u16 ? p0[1] : p0[0]) + r0;
        p1[0] = (u16 ? p1[1] : p1[0]) + r1;
      }
      p0[0] += __shfl_xor(p0[0], 32);   // d=32: allreduce last n4 bit
      p1[0] += __shfl_xor(p1[0], 32);
      if ((l & 32) == 0) {
        int qf = (u2 ? 8 : 0) + (u4 ? 4 : 0) + (u8 ? 2 : 0) + (u16 ? 1 : 0);
        cxs[0][c][s * 16 + qf] = p0[0];
        cxs[1][c][s * 16 + qf] = p1[0];
      }
    }
    __syncthreads();

    // --- A: partA[o][c][j] = sum_i cxs[o][c][i] * W[c][o0+o][i][j] ---
    {
      int o = tid >> 9, cA = (tid >> 5) & 15, j = tid & 31;
      const float* Wp = W + (((size_t)(cA * OO + o0 + o)) * II) * JJ + j;
      float acc = 0.f;
      #pragma unroll 8
      for (int i = 0; i < II; ++i)
        acc += cxs[o][cA][i] * Wp[i * JJ];   // cxs broadcast, W j-coalesced
      partA[o][cA][j] = acc;
    }
    __syncthreads();

    // --- A-reduce + squash (final iter writes output) ---
    if (tid < 64) {
      int o = tid >> 5, j = tid & 31;
      float sA = 0.f;
      #pragma unroll
      for (int cR = 0; cR < CC; ++cR) sA += partA[o][cR][j];
      float msq = sA * sA;
      #pragma unroll
      for (int off = 16; off > 0; off >>= 1) msq += __shfl_xor(msq, off);
      float mag = sqrtf(msq) + EPS_;
      float a   = msq / (1.0f + msq);
      float vvq = a * sA / mag;
      if (it == 2) {
        int row = b * OO + (o0 + o);
        out[(size_t)row * JJ + j] = vvq;               // v_j: [B,1,O,J] flat
        if (j == 0) out[BB * OO * JJ + row] = a;       // a_j: [B,1,O,1] flat
      } else {
        vs[o][j] = vvq;
      }
    }
    if (it == 2) break;                   // uniform exit
    __syncthreads();

    // --- Wv: wv[o][c][i] = sum_j W[c][o0+o][i][j] * vs[o][j] ---
    {
      int o = tid >> 9, cW = (tid >> 5) & 15, i = tid & 31;
      const float4* Wr = (const float4*)(W + (((size_t)(cW * OO + o0 + o)) * II + i) * JJ);
      float acc = 0.f;
      #pragma unroll 4
      for (int q = 0; q < 8; ++q) {
        float4 w4 = Wr[q];
        acc += w4.x * vs[o][q*4+0] + w4.y * vs[o][q*4+1]
             + w4.z * vs[o][q*4+2] + w4.w * vs[o][q*4+3];
      }
      wv[o][cW][i] = acc;
    }
    __syncthreads();

    // --- U: bijL += x.wv (x from regs); stats + next coef, fused ---
    {
      float4 ac0 = make_float4(0.f,0.f,0.f,0.f);
      float4 ac1 = make_float4(0.f,0.f,0.f,0.f);
      #pragma unroll
      for (int q = 0; q < 16; ++q) {
        int i = s * 16 + q;
        float w0 = wv[0][c][i], w1 = wv[1][c][i];   // 2-addr broadcasts
        ac0.x += xv[q].x * w0; ac0.y += xv[q].y * w0;
        ac0.z += xv[q].z * w0; ac0.w += xv[q].w * w0;
        ac1.x += xv[q].x * w1; ac1.y += xv[q].y * w1;
        ac1.z += xv[q].z * w1; ac1.w += xv[q].w * w1;
      }
      // combine i-halves across the s-pair
      ac0.x += __shfl_xor(ac0.x, 1); ac0.y += __shfl_xor(ac0.y, 1);
      ac0.z += __shfl_xor(ac0.z, 1); ac0.w += __shfl_xor(ac0.w, 1);
      ac1.x += __shfl_xor(ac1.x, 1); ac1.y += __shfl_xor(ac1.y, 1);
      ac1.z += __shfl_xor(ac1.z, 1); ac1.w += __shfl_xor(ac1.w, 1);
      float4 r = (s == 0) ? ac0 : ac1;              // lane s owns o=s
      float4 bb = *(const float4*)(&bijL[s][c][n4 * 4]);
      r.x += bb.x; r.y += bb.y; r.z += bb.z; r.w += bb.w;
      *(float4*)(&bijL[s][c][n4 * 4]) = r;

      // per-wave max partials (parity-preserving: offsets 2..32)
      float m4 = fmaxf(fmaxf(r.x, r.y), fmaxf(r.z, r.w));
      #pragma unroll
      for (int off = 2; off <= 32; off <<= 1) m4 = fmaxf(m4, __shfl_xor(m4, off));
      int wave = tid >> 6;
      if ((tid & 63) <= 1) redM[wave][s] = m4;      // lane 0: o=0, lane 1: o=1
      __syncthreads();
      float mo = redM[0][s];                        // every thread reduces locally
      #pragma unroll
      for (int w2 = 1; w2 < CC; ++w2) mo = fmaxf(mo, redM[w2][s]);
      float ex = __expf(r.x - mo), ey = __expf(r.y - mo),
            ez = __expf(r.z - mo), ew = __expf(r.w - mo);
      float e = ex + ey + ez + ew;
      #pragma unroll
      for (int off = 2; off <= 32; off <<= 1) e += __shfl_xor(e, off);
      if ((tid & 63) <= 1) redE[wave][s] = e;
      __syncthreads();
      float ss = redE[0][s];
      #pragma unroll
      for (int w2 = 1; w2 < CC; ++w2) ss += redE[w2][s];
      float rin = 1.0f / ss;
      // coef for the next iteration: reuse the exp values already computed
      *(float4*)(&coef[s][c][n4 * 4]) =
          make_float4(ex * rin, ey * rin, ez * rin, ew * rin);
    }
    __syncthreads();
  }
}

extern "C" void kernel_launch(void* const* d_in, const int* in_sizes, int n_in,
                              void* d_out, int out_size, void* d_ws, size_t ws_size,
                              hipStream_t stream) {
  const float* x = (const float*)d_in[0];   // [B,N,C,I]
  const float* W = (const float*)d_in[1];   // [C,O,I,J]
  (void)in_sizes; (void)n_in;               // d_in[2] = number_of_nodes (fixed 128)
  float* out = (float*)d_out; (void)out_size;

  float* xT = (float*)d_ws;                 // 2,097,152 floats (8 MB), i-major
  (void)ws_size;

  k_transpose<<<BB * CC, 1024, 0, stream>>>(x, xT);
  k_route<<<BB * (OO / 2), 1024, 0, stream>>>(xT, W, out);
}